// Round 1
// baseline (2927.411 us; speedup 1.0000x reference)
//
#include <hip/hip_runtime.h>

#define N_NODES 100000
#define N_EDGES 50000
#define M_INC   1600000
#define D_HID   64

// ---------------- kernels ----------------

// One thread per incidence: accumulate node degree (weighted) and edge cardinality.
__global__ void degrees_kernel(const int* __restrict__ node_idx,
                               const int* __restrict__ edge_idx,
                               const float* __restrict__ ew,
                               float* __restrict__ Dn,
                               float* __restrict__ Be) {
    int m = blockIdx.x * 256 + threadIdx.x;
    if (m < M_INC) {
        int e = edge_idx[m];
        atomicAdd(&Dn[node_idx[m]], ew[e]);
        atomicAdd(&Be[e], 1.0f);
    }
}

// In-place safe reciprocal for Dn (N_NODES) and Be (N_EDGES).
__global__ void recip_kernel(float* __restrict__ Dn, float* __restrict__ Be) {
    int i = blockIdx.x * 256 + threadIdx.x;
    if (i < N_NODES) { float v = Dn[i]; Dn[i] = (v > 0.f) ? (1.0f / v) : 0.f; }
    if (i < N_EDGES) { float v = Be[i]; Be[i] = (v > 0.f) ? (1.0f / v) : 0.f; }
}

// Stage 1: scatter x rows into edge_feat (raw sums). 16 lanes per incidence,
// each lane handles one float4 (4 dword atomics).
__global__ void stage1_kernel(const int* __restrict__ node_idx,
                              const int* __restrict__ edge_idx,
                              const float* __restrict__ x,
                              float* __restrict__ ef) {
    int t = blockIdx.x * 256 + threadIdx.x;
    int m = t >> 4;
    int lane = t & 15;
    if (m >= M_INC) return;
    int n = node_idx[m];
    int e = edge_idx[m];
    float4 v = ((const float4*)x)[n * 16 + lane];
    float* dst = ef + (size_t)e * D_HID + lane * 4;
    atomicAdd(dst + 0, v.x);
    atomicAdd(dst + 1, v.y);
    atomicAdd(dst + 2, v.z);
    atomicAdd(dst + 3, v.w);
}

// Scale edge_feat rows by Be_recip (one pass over 50000x64).
__global__ void scale_ef_kernel(float* __restrict__ ef, const float* __restrict__ Be) {
    int i = blockIdx.x * 256 + threadIdx.x;   // float4 index
    if (i < N_EDGES * 16) {
        float s = Be[i >> 4];
        float4* p = (float4*)ef;
        float4 v = p[i];
        v.x *= s; v.y *= s; v.z *= s; v.w *= s;
        p[i] = v;
    }
}

// Stage 2: scatter edge_feat rows into node accumulator (d_out used as acc).
__global__ void stage2_kernel(const int* __restrict__ node_idx,
                              const int* __restrict__ edge_idx,
                              const float* __restrict__ ef,
                              float* __restrict__ acc) {
    int t = blockIdx.x * 256 + threadIdx.x;
    int m = t >> 4;
    int lane = t & 15;
    if (m >= M_INC) return;
    int n = node_idx[m];
    int e = edge_idx[m];
    float4 v = ((const float4*)ef)[e * 16 + lane];
    float* dst = acc + (size_t)n * D_HID + lane * 4;
    atomicAdd(dst + 0, v.x);
    atomicAdd(dst + 1, v.y);
    atomicAdd(dst + 2, v.z);
    atomicAdd(dst + 3, v.w);
}

// Finalize: out = 0.5 * (x + Dn_recip[n] * acc)   (acc is in d_out, in-place).
__global__ void finalize_kernel(const float* __restrict__ x,
                                const float* __restrict__ Dn,
                                float* __restrict__ out) {
    int i = blockIdx.x * 256 + threadIdx.x;   // float4 index over N_NODES*16
    if (i < N_NODES * 16) {
        float s = Dn[i >> 4];
        float4 a = ((float4*)out)[i];
        float4 xv = ((const float4*)x)[i];
        float4 r;
        r.x = 0.5f * (xv.x + s * a.x);
        r.y = 0.5f * (xv.y + s * a.y);
        r.z = 0.5f * (xv.z + s * a.z);
        r.w = 0.5f * (xv.w + s * a.w);
        ((float4*)out)[i] = r;
    }
}

// ---------------- launch ----------------

extern "C" void kernel_launch(void* const* d_in, const int* in_sizes, int n_in,
                              void* d_out, int out_size, void* d_ws, size_t ws_size,
                              hipStream_t stream) {
    const float* x        = (const float*)d_in[0];
    const int*   node_idx = (const int*)d_in[1];
    const int*   edge_idx = (const int*)d_in[2];
    const float* ew       = (const float*)d_in[3];
    float* out = (float*)d_out;

    // Workspace layout (floats): Dn [0,100000) | Be [100000,150000) | ef [150000, 150000+3200000)
    float* Dn = (float*)d_ws;
    float* Be = Dn + N_NODES;
    float* ef = Dn + (N_NODES + N_EDGES);   // offset 150000 floats, 16B-aligned

    size_t ws_zero_bytes = (size_t)(N_NODES + N_EDGES + (size_t)N_EDGES * D_HID) * sizeof(float);
    hipMemsetAsync(d_ws, 0, ws_zero_bytes, stream);
    hipMemsetAsync(d_out, 0, (size_t)N_NODES * D_HID * sizeof(float), stream);

    degrees_kernel<<<(M_INC + 255) / 256, 256, 0, stream>>>(node_idx, edge_idx, ew, Dn, Be);
    recip_kernel<<<(N_NODES + 255) / 256, 256, 0, stream>>>(Dn, Be);
    stage1_kernel<<<(M_INC * 16 + 255) / 256, 256, 0, stream>>>(node_idx, edge_idx, x, ef);
    scale_ef_kernel<<<(N_EDGES * 16 + 255) / 256, 256, 0, stream>>>(ef, Be);
    stage2_kernel<<<(M_INC * 16 + 255) / 256, 256, 0, stream>>>(node_idx, edge_idx, ef, out);
    finalize_kernel<<<(N_NODES * 16 + 255) / 256, 256, 0, stream>>>(x, Dn, out);
}

// Round 2
// 808.136 us; speedup vs baseline: 3.6224x; 3.6224x over previous
//
#include <hip/hip_runtime.h>

#define N_NODES 100000
#define N_EDGES 50000
#define M_INC   1600000
#define D_HID   64

// ---- workspace layout (4-byte element offsets) ----
#define OFF_NODE_CNT 0                 // int   [100000]
#define OFF_EDGE_CNT 100000            // int   [50000]
#define OFF_DN       150000            // float [100000]  (weighted degree -> recip in place)
#define OFF_NODE_CUR 250000            // int   [100000]
#define OFF_EDGE_CUR 350000            // int   [50000]
#define OFF_BER      400000            // float [50000]
#define ZERO_FLOATS  450000            // everything above must be zeroed
#define OFF_NODE_OFF 450000            // int   [100001]
#define OFF_EDGE_OFF 550004            // int   [50001]
#define OFF_NODE_CSR 600008            // int   [1600000] edge ids grouped by node
#define OFF_EDGE_CSR 2200008           // int   [1600000] node ids grouped by edge
#define OFF_EF       3800008           // float [3200000]

// 1 thread / incidence: integer counts for CSR + weighted node degree.
__global__ void counts_kernel(const int* __restrict__ node_idx,
                              const int* __restrict__ edge_idx,
                              const float* __restrict__ ew,
                              int* __restrict__ ncnt, int* __restrict__ ecnt,
                              float* __restrict__ Dn) {
    int m = blockIdx.x * 256 + threadIdx.x;
    if (m < M_INC) {
        int n = node_idx[m], e = edge_idx[m];
        atomicAdd(&ncnt[n], 1);
        atomicAdd(&ecnt[e], 1);
        atomicAdd(&Dn[n], ew[e]);
    }
}

// Two blocks of 1024: block 0 scans edge counts, block 1 scans node counts.
// Exclusive scan; dst has n+1 entries (dst[n] = total).
__global__ void scan2_kernel(const int* __restrict__ ecnt, const int* __restrict__ ncnt,
                             int* __restrict__ eoff, int* __restrict__ noff) {
    __shared__ int lds[1024];
    const int t = threadIdx.x;
    const int n = (blockIdx.x == 0) ? N_EDGES : N_NODES;
    const int* src = (blockIdx.x == 0) ? ecnt : ncnt;
    int* dst = (blockIdx.x == 0) ? eoff : noff;
    const int chunk = (n + 1023) / 1024;
    const int lo = t * chunk;
    const int hi = (lo + chunk < n) ? lo + chunk : n;
    int s = 0;
    for (int i = lo; i < hi; i++) s += src[i];
    lds[t] = s;
    __syncthreads();
    // Hillis-Steele inclusive scan over 1024 partials
    for (int off = 1; off < 1024; off <<= 1) {
        int add = (t >= off) ? lds[t - off] : 0;
        __syncthreads();
        lds[t] += add;
        __syncthreads();
    }
    int run = (t > 0) ? lds[t - 1] : 0;   // exclusive prefix of this thread's chunk
    for (int i = lo; i < hi; i++) { dst[i] = run; run += src[i]; }
    if (t == 1023) dst[n] = lds[1023];
}

// Reciprocals: DnR in place from Dn; BeR from integer edge counts.
__global__ void recip_kernel(float* __restrict__ Dn, const int* __restrict__ ecnt,
                             float* __restrict__ BeR) {
    int i = blockIdx.x * 256 + threadIdx.x;
    if (i < N_NODES) { float v = Dn[i]; Dn[i] = (v > 0.f) ? (1.0f / v) : 0.f; }
    if (i < N_EDGES) { int c = ecnt[i]; BeR[i] = (c > 0) ? (1.0f / (float)c) : 0.f; }
}

// Counting-sort fill: scatter each incidence into both CSR orderings.
__global__ void fill_kernel(const int* __restrict__ node_idx,
                            const int* __restrict__ edge_idx,
                            const int* __restrict__ noff, const int* __restrict__ eoff,
                            int* __restrict__ ncur, int* __restrict__ ecur,
                            int* __restrict__ node_csr, int* __restrict__ edge_csr) {
    int m = blockIdx.x * 256 + threadIdx.x;
    if (m < M_INC) {
        int n = node_idx[m], e = edge_idx[m];
        int pe = atomicAdd(&ecur[e], 1);
        edge_csr[eoff[e] + pe] = n;
        int pn = atomicAdd(&ncur[n], 1);
        node_csr[noff[n] + pn] = e;
    }
}

// Stage 1: one wave per edge; lane l owns feature column l.
// ef[e][l] = BeR[e] * sum_{n in edge e} x[n][l]
__global__ void stage1_kernel(const int* __restrict__ eoff, const int* __restrict__ ecsr,
                              const float* __restrict__ x, const float* __restrict__ BeR,
                              float* __restrict__ ef) {
    int wid = (blockIdx.x * 256 + threadIdx.x) >> 6;
    int lane = threadIdx.x & 63;
    if (wid >= N_EDGES) return;
    int s = eoff[wid], t = eoff[wid + 1];
    float acc = 0.f;
    for (int base = s; base < t; base += 64) {
        int cnt = t - base; if (cnt > 64) cnt = 64;
        int myidx = (base + lane < t) ? ecsr[base + lane] : 0;
        for (int j = 0; j < cnt; j++) {
            int n = __shfl(myidx, j, 64);
            acc += x[(size_t)n * D_HID + lane];
        }
    }
    ef[(size_t)wid * D_HID + lane] = acc * BeR[wid];
}

// Stage 2: one wave per node; out[n][l] = 0.5*(x[n][l] + DnR[n]*sum ef[e][l])
__global__ void stage2_kernel(const int* __restrict__ noff, const int* __restrict__ ncsr,
                              const float* __restrict__ ef, const float* __restrict__ DnR,
                              const float* __restrict__ x, float* __restrict__ out) {
    int wid = (blockIdx.x * 256 + threadIdx.x) >> 6;
    int lane = threadIdx.x & 63;
    if (wid >= N_NODES) return;
    int s = noff[wid], t = noff[wid + 1];
    float acc = 0.f;
    for (int base = s; base < t; base += 64) {
        int cnt = t - base; if (cnt > 64) cnt = 64;
        int myidx = (base + lane < t) ? ncsr[base + lane] : 0;
        for (int j = 0; j < cnt; j++) {
            int e = __shfl(myidx, j, 64);
            acc += ef[(size_t)e * D_HID + lane];
        }
    }
    size_t o = (size_t)wid * D_HID + lane;
    out[o] = 0.5f * (x[o] + DnR[wid] * acc);
}

extern "C" void kernel_launch(void* const* d_in, const int* in_sizes, int n_in,
                              void* d_out, int out_size, void* d_ws, size_t ws_size,
                              hipStream_t stream) {
    const float* x        = (const float*)d_in[0];
    const int*   node_idx = (const int*)d_in[1];
    const int*   edge_idx = (const int*)d_in[2];
    const float* ew       = (const float*)d_in[3];
    float* out = (float*)d_out;

    char* ws = (char*)d_ws;
    int*   ncnt     = (int*)  (ws) + OFF_NODE_CNT;
    int*   ecnt     = (int*)  (ws) + OFF_EDGE_CNT;
    float* Dn       = (float*)(ws) + OFF_DN;
    int*   ncur     = (int*)  (ws) + OFF_NODE_CUR;
    int*   ecur     = (int*)  (ws) + OFF_EDGE_CUR;
    float* BeR      = (float*)(ws) + OFF_BER;
    int*   noff     = (int*)  (ws) + OFF_NODE_OFF;
    int*   eoff     = (int*)  (ws) + OFF_EDGE_OFF;
    int*   node_csr = (int*)  (ws) + OFF_NODE_CSR;
    int*   edge_csr = (int*)  (ws) + OFF_EDGE_CSR;
    float* ef       = (float*)(ws) + OFF_EF;

    // Zero counts/cursors/Dn (contiguous prefix of ws).
    hipMemsetAsync(d_ws, 0, (size_t)ZERO_FLOATS * 4, stream);

    counts_kernel<<<(M_INC + 255) / 256, 256, 0, stream>>>(node_idx, edge_idx, ew, ncnt, ecnt, Dn);
    scan2_kernel<<<2, 1024, 0, stream>>>(ecnt, ncnt, eoff, noff);
    recip_kernel<<<(N_NODES + 255) / 256, 256, 0, stream>>>(Dn, ecnt, BeR);
    fill_kernel<<<(M_INC + 255) / 256, 256, 0, stream>>>(node_idx, edge_idx, noff, eoff,
                                                         ncur, ecur, node_csr, edge_csr);
    stage1_kernel<<<(N_EDGES * 64 + 255) / 256, 256, 0, stream>>>(eoff, edge_csr, x, BeR, ef);
    stage2_kernel<<<(N_NODES * 64 + 255) / 256, 256, 0, stream>>>(noff, node_csr, ef, Dn, x, out);
}

// Round 3
// 531.082 us; speedup vs baseline: 5.5122x; 1.5217x over previous
//
#include <hip/hip_runtime.h>

#define N_NODES 100000
#define N_EDGES 50000
#define M_INC   1600000
#define D_HID   64

// ---- workspace layout (byte offsets; d_ws is >=256B aligned) ----
// ncnt     [100000 int]  @ 0
// ecnt     [ 50000 int]  @ 400000        (zero first 600000 bytes)
// ranks    [1.6M  u32]   @ 600000        (rank_n<<16 | rank_e)
// noff     [100001 int]  @ 7000000
// eoff     [ 50001 int]  @ 7400004
// node_csr [1.6M  int]   @ 7600008       (edge ids grouped by node)
// edge_csr [1.6M  int]   @ 14000008      (node ids grouped by edge)
// ef       [3.2M  float] @ 20400016      (16B aligned)

// Pass A: count segment sizes AND capture each incidence's rank within both
// segments (the atomicAdd return value). 2 atomics/incidence total.
__global__ void passA_kernel(const int* __restrict__ node_idx,
                             const int* __restrict__ edge_idx,
                             int* __restrict__ ncnt, int* __restrict__ ecnt,
                             unsigned int* __restrict__ ranks) {
    int m = blockIdx.x * 256 + threadIdx.x;
    if (m < M_INC) {
        int n = node_idx[m], e = edge_idx[m];
        unsigned pn = (unsigned)atomicAdd(&ncnt[n], 1);
        unsigned pe = (unsigned)atomicAdd(&ecnt[e], 1);
        ranks[m] = (pn << 16) | pe;   // segment sizes << 65536, guaranteed
    }
}

// Two blocks of 1024: block 0 scans edge counts, block 1 scans node counts.
// Exclusive scan; dst has n+1 entries (dst[n] = total).
__global__ void scan2_kernel(const int* __restrict__ ecnt, const int* __restrict__ ncnt,
                             int* __restrict__ eoff, int* __restrict__ noff) {
    __shared__ int lds[1024];
    const int t = threadIdx.x;
    const int n = (blockIdx.x == 0) ? N_EDGES : N_NODES;
    const int* src = (blockIdx.x == 0) ? ecnt : ncnt;
    int* dst = (blockIdx.x == 0) ? eoff : noff;
    const int chunk = (n + 1023) / 1024;
    const int lo = t * chunk;
    const int hi = (lo + chunk < n) ? lo + chunk : n;
    int s = 0;
    for (int i = lo; i < hi; i++) s += src[i];
    lds[t] = s;
    __syncthreads();
    for (int off = 1; off < 1024; off <<= 1) {
        int add = (t >= off) ? lds[t - off] : 0;
        __syncthreads();
        lds[t] += add;
        __syncthreads();
    }
    int run = (t > 0) ? lds[t - 1] : 0;
    for (int i = lo; i < hi; i++) { dst[i] = run; run += src[i]; }
    if (t == 1023) dst[n] = lds[1023];
}

// Fill: atomic-free counting-sort scatter using the captured ranks.
__global__ void fill_kernel(const int* __restrict__ node_idx,
                            const int* __restrict__ edge_idx,
                            const unsigned int* __restrict__ ranks,
                            const int* __restrict__ noff, const int* __restrict__ eoff,
                            int* __restrict__ node_csr, int* __restrict__ edge_csr) {
    int m = blockIdx.x * 256 + threadIdx.x;
    if (m < M_INC) {
        int n = node_idx[m], e = edge_idx[m];
        unsigned rp = ranks[m];
        edge_csr[eoff[e] + (int)(rp & 0xffffu)] = n;
        node_csr[noff[n] + (int)(rp >> 16)] = e;
    }
}

// Stage 1: one wave per edge. Lanes split as 4 groups x 16; group g processes
// member (4j+g), lane gl within a group owns feature columns 4*gl..4*gl+3
// (one float4). Be comes free from the offset difference.
__global__ void stage1_kernel(const int* __restrict__ eoff, const int* __restrict__ ecsr,
                              const float* __restrict__ x, float* __restrict__ ef) {
    int wid = (blockIdx.x * 256 + threadIdx.x) >> 6;
    if (wid >= N_EDGES) return;
    int lane = threadIdx.x & 63;
    int group = lane >> 4;
    int gl = lane & 15;
    int s = eoff[wid], t = eoff[wid + 1];
    float4 acc = make_float4(0.f, 0.f, 0.f, 0.f);
    for (int base = s; base < t; base += 64) {
        int idx_l = (base + lane < t) ? ecsr[base + lane] : 0;
        int cnt = t - base; if (cnt > 64) cnt = 64;
        int steps = (cnt + 3) >> 2;
        for (int j = 0; j < steps; j++) {
            int p = 4 * j + group;
            int mi = __shfl(idx_l, p, 64);
            if (p < cnt) {
                float4 v = ((const float4*)x)[(size_t)mi * 16 + gl];
                acc.x += v.x; acc.y += v.y; acc.z += v.z; acc.w += v.w;
            }
        }
    }
    for (int off = 16; off < 64; off <<= 1) {
        acc.x += __shfl_xor(acc.x, off, 64);
        acc.y += __shfl_xor(acc.y, off, 64);
        acc.z += __shfl_xor(acc.z, off, 64);
        acc.w += __shfl_xor(acc.w, off, 64);
    }
    if (group == 0) {
        int card = t - s;
        float ber = (card > 0) ? (1.0f / (float)card) : 0.f;
        float4 r = make_float4(acc.x * ber, acc.y * ber, acc.z * ber, acc.w * ber);
        ((float4*)ef)[(size_t)wid * 16 + gl] = r;
    }
}

// Stage 2: one wave per node, same lane layout. Dn computed inline by
// gathering ew for the node's member edges during the CSR chunk load.
__global__ void stage2_kernel(const int* __restrict__ noff, const int* __restrict__ ncsr,
                              const float* __restrict__ ef, const float* __restrict__ ew,
                              const float* __restrict__ x, float* __restrict__ out) {
    int wid = (blockIdx.x * 256 + threadIdx.x) >> 6;
    if (wid >= N_NODES) return;
    int lane = threadIdx.x & 63;
    int group = lane >> 4;
    int gl = lane & 15;
    int s = noff[wid], t = noff[wid + 1];
    float4 acc = make_float4(0.f, 0.f, 0.f, 0.f);
    float dn = 0.f;
    for (int base = s; base < t; base += 64) {
        bool lv = (base + lane < t);
        int idx_l = lv ? ncsr[base + lane] : 0;
        if (lv) dn += ew[idx_l];
        int cnt = t - base; if (cnt > 64) cnt = 64;
        int steps = (cnt + 3) >> 2;
        for (int j = 0; j < steps; j++) {
            int p = 4 * j + group;
            int mi = __shfl(idx_l, p, 64);
            if (p < cnt) {
                float4 v = ((const float4*)ef)[(size_t)mi * 16 + gl];
                acc.x += v.x; acc.y += v.y; acc.z += v.z; acc.w += v.w;
            }
        }
    }
    for (int off = 1; off < 64; off <<= 1) dn += __shfl_xor(dn, off, 64);
    for (int off = 16; off < 64; off <<= 1) {
        acc.x += __shfl_xor(acc.x, off, 64);
        acc.y += __shfl_xor(acc.y, off, 64);
        acc.z += __shfl_xor(acc.z, off, 64);
        acc.w += __shfl_xor(acc.w, off, 64);
    }
    if (group == 0) {
        float dnr = (dn > 0.f) ? (1.0f / dn) : 0.f;
        float4 xv = ((const float4*)x)[(size_t)wid * 16 + gl];
        float4 r;
        r.x = 0.5f * (xv.x + dnr * acc.x);
        r.y = 0.5f * (xv.y + dnr * acc.y);
        r.z = 0.5f * (xv.z + dnr * acc.z);
        r.w = 0.5f * (xv.w + dnr * acc.w);
        ((float4*)out)[(size_t)wid * 16 + gl] = r;
    }
}

extern "C" void kernel_launch(void* const* d_in, const int* in_sizes, int n_in,
                              void* d_out, int out_size, void* d_ws, size_t ws_size,
                              hipStream_t stream) {
    const float* x        = (const float*)d_in[0];
    const int*   node_idx = (const int*)d_in[1];
    const int*   edge_idx = (const int*)d_in[2];
    const float* ew       = (const float*)d_in[3];
    float* out = (float*)d_out;

    char* ws = (char*)d_ws;
    int*          ncnt     = (int*)(ws + 0);
    int*          ecnt     = (int*)(ws + 400000);
    unsigned int* ranks    = (unsigned int*)(ws + 600000);
    int*          noff     = (int*)(ws + 7000000);
    int*          eoff     = (int*)(ws + 7400004);
    int*          node_csr = (int*)(ws + 7600008);
    int*          edge_csr = (int*)(ws + 14000008);
    float*        ef       = (float*)(ws + 20400016);

    hipMemsetAsync(d_ws, 0, 600000, stream);   // ncnt + ecnt only

    passA_kernel<<<(M_INC + 255) / 256, 256, 0, stream>>>(node_idx, edge_idx, ncnt, ecnt, ranks);
    scan2_kernel<<<2, 1024, 0, stream>>>(ecnt, ncnt, eoff, noff);
    fill_kernel<<<(M_INC + 255) / 256, 256, 0, stream>>>(node_idx, edge_idx, ranks,
                                                         noff, eoff, node_csr, edge_csr);
    stage1_kernel<<<(N_EDGES * 64 + 255) / 256, 256, 0, stream>>>(eoff, edge_csr, x, ef);
    stage2_kernel<<<(N_NODES * 64 + 255) / 256, 256, 0, stream>>>(noff, node_csr, ef, ew, x, out);
}

// Round 4
// 385.052 us; speedup vs baseline: 7.6026x; 1.3792x over previous
//
#include <hip/hip_runtime.h>

#define N_NODES 100000
#define N_EDGES 50000
#define M_INC   1600000
#define D_HID   64

#define N_TILES_N 25   // ceil(100000/4096)
#define N_TILES_E 13   // ceil(50000/4096)

// ---- workspace layout (byte offsets) ----
// ncnt     [100000 int]  @ 0              \ contiguous 150000-int count array
// ecnt     [ 50000 int]  @ 400000         /  (zero first 600000 bytes)
// ranks    [1.6M  u32]   @ 600000         (rank_n<<16 | rank_e)
// noff     [100001 int]  @ 7000000        (16B aligned)
// eoff     [ 50001 int]  @ 7400016        (16B aligned)
// node_csr [1.6M  int]   @ 7600032
// edge_csr [1.6M  int]   @ 14000032
// ef       [3.2M  float] @ 20400032       (16B aligned; scan scratch lives here pre-stage1)

// Pass A: count segment sizes AND capture each incidence's rank within both
// segments (the atomicAdd return value). 2 atomics/incidence total.
__global__ void passA_kernel(const int* __restrict__ node_idx,
                             const int* __restrict__ edge_idx,
                             int* __restrict__ ncnt, int* __restrict__ ecnt,
                             unsigned int* __restrict__ ranks) {
    int m = blockIdx.x * 256 + threadIdx.x;
    if (m < M_INC) {
        int n = node_idx[m], e = edge_idx[m];
        unsigned pn = (unsigned)atomicAdd(&ncnt[n], 1);
        unsigned pe = (unsigned)atomicAdd(&ecnt[e], 1);
        ranks[m] = (pn << 16) | pe;   // segment sizes << 65536, guaranteed
    }
}

// Scan stage 1: per-tile (4096 elements) sums over the contiguous count array.
// Blocks 0..24 = node tiles, 25..37 = edge tiles.
__global__ void scan_partial_kernel(const int* __restrict__ cnt,
                                    int* __restrict__ pn, int* __restrict__ pe) {
    __shared__ int lds[16];
    int b = blockIdx.x;
    const int* src; int nElem; int tile; int* dst;
    if (b < N_TILES_N) { src = cnt;            nElem = N_NODES; tile = b;             dst = pn; }
    else               { src = cnt + N_NODES;  nElem = N_EDGES; tile = b - N_TILES_N; dst = pe; }
    int t = threadIdx.x;
    int i4 = tile * 1024 + t;
    int sum = 0;
    if (i4 * 4 < nElem) {
        int4 v = ((const int4*)src)[i4];
        sum = v.x + v.y + v.z + v.w;
    }
    for (int off = 1; off < 64; off <<= 1) sum += __shfl_xor(sum, off, 64);
    if ((t & 63) == 0) lds[t >> 6] = sum;
    __syncthreads();
    if (t < 16) {
        int s = lds[t];
        for (int off = 1; off < 16; off <<= 1) s += __shfl_xor(s, off, 64);
        if (t == 0) dst[tile] = s;
    }
}

// Scan stage 2: exclusive scan of tile sums (one wave per segment); writes
// sentinel offsets noff[N_NODES], eoff[N_EDGES].
__global__ void scan_base_kernel(const int* __restrict__ pn, const int* __restrict__ pe,
                                 int* __restrict__ bn, int* __restrict__ be,
                                 int* __restrict__ noff, int* __restrict__ eoff) {
    int w = threadIdx.x >> 6;
    int lane = threadIdx.x & 63;
    if (w == 0) {
        int v = (lane < N_TILES_N) ? pn[lane] : 0;
        int incl = v;
        for (int d = 1; d < 64; d <<= 1) { int u = __shfl_up(incl, d, 64); if (lane >= d) incl += u; }
        if (lane < N_TILES_N) bn[lane] = incl - v;
        if (lane == N_TILES_N - 1) noff[N_NODES] = incl;
    } else {
        int v = (lane < N_TILES_E) ? pe[lane] : 0;
        int incl = v;
        for (int d = 1; d < 64; d <<= 1) { int u = __shfl_up(incl, d, 64); if (lane >= d) incl += u; }
        if (lane < N_TILES_E) be[lane] = incl - v;
        if (lane == N_TILES_E - 1) eoff[N_EDGES] = incl;
    }
}

// Scan stage 3: block-level exclusive scan of each tile + tile base, int4 I/O.
__global__ void scan_write_kernel(const int* __restrict__ cnt,
                                  const int* __restrict__ bn, const int* __restrict__ be,
                                  int* __restrict__ noff, int* __restrict__ eoff) {
    __shared__ int wsum[16];
    int b = blockIdx.x;
    const int* src; int* dst; int nElem; int tile; int tbase;
    if (b < N_TILES_N) { src = cnt;           dst = noff; nElem = N_NODES; tile = b;             tbase = bn[tile]; }
    else               { src = cnt + N_NODES; dst = eoff; nElem = N_EDGES; tile = b - N_TILES_N; tbase = be[tile]; }
    int t = threadIdx.x;
    int lane = t & 63, w = t >> 6;
    int i4 = tile * 1024 + t;
    int4 c = make_int4(0, 0, 0, 0);
    bool valid = (i4 * 4 < nElem);
    if (valid) c = ((const int4*)src)[i4];
    int tsum = c.x + c.y + c.z + c.w;
    int incl = tsum;
    for (int d = 1; d < 64; d <<= 1) { int u = __shfl_up(incl, d, 64); if (lane >= d) incl += u; }
    if (lane == 63) wsum[w] = incl;
    __syncthreads();
    if (t < 16) {
        int v = wsum[t];
        int wi = v;
        for (int d = 1; d < 16; d <<= 1) { int u = __shfl_up(wi, d, 64); if (t >= d) wi += u; }
        wsum[t] = wi - v;   // exclusive wave base
    }
    __syncthreads();
    int ex = tbase + wsum[w] + incl - tsum;
    if (valid) {
        int4 o;
        o.x = ex; o.y = ex + c.x; o.z = o.y + c.y; o.w = o.z + c.z;
        ((int4*)dst)[i4] = o;
    }
}

// Fill: atomic-free counting-sort scatter using the captured ranks.
__global__ void fill_kernel(const int* __restrict__ node_idx,
                            const int* __restrict__ edge_idx,
                            const unsigned int* __restrict__ ranks,
                            const int* __restrict__ noff, const int* __restrict__ eoff,
                            int* __restrict__ node_csr, int* __restrict__ edge_csr) {
    int m = blockIdx.x * 256 + threadIdx.x;
    if (m < M_INC) {
        int n = node_idx[m], e = edge_idx[m];
        unsigned rp = ranks[m];
        edge_csr[eoff[e] + (int)(rp & 0xffffu)] = n;
        node_csr[noff[n] + (int)(rp >> 16)] = e;
    }
}

// Stage 1: one wave per edge; 4 member-groups x 16 lanes, float4 per lane.
__global__ void stage1_kernel(const int* __restrict__ eoff, const int* __restrict__ ecsr,
                              const float* __restrict__ x, float* __restrict__ ef) {
    int wid = (blockIdx.x * 256 + threadIdx.x) >> 6;
    if (wid >= N_EDGES) return;
    int lane = threadIdx.x & 63;
    int group = lane >> 4;
    int gl = lane & 15;
    int s = eoff[wid], t = eoff[wid + 1];
    float4 acc = make_float4(0.f, 0.f, 0.f, 0.f);
    for (int base = s; base < t; base += 64) {
        int idx_l = (base + lane < t) ? ecsr[base + lane] : 0;
        int cnt = t - base; if (cnt > 64) cnt = 64;
        int steps = (cnt + 3) >> 2;
        for (int j = 0; j < steps; j++) {
            int p = 4 * j + group;
            int mi = __shfl(idx_l, p, 64);
            if (p < cnt) {
                float4 v = ((const float4*)x)[(size_t)mi * 16 + gl];
                acc.x += v.x; acc.y += v.y; acc.z += v.z; acc.w += v.w;
            }
        }
    }
    for (int off = 16; off < 64; off <<= 1) {
        acc.x += __shfl_xor(acc.x, off, 64);
        acc.y += __shfl_xor(acc.y, off, 64);
        acc.z += __shfl_xor(acc.z, off, 64);
        acc.w += __shfl_xor(acc.w, off, 64);
    }
    if (group == 0) {
        int card = t - s;
        float ber = (card > 0) ? (1.0f / (float)card) : 0.f;
        ((float4*)ef)[(size_t)wid * 16 + gl] =
            make_float4(acc.x * ber, acc.y * ber, acc.z * ber, acc.w * ber);
    }
}

// Stage 2: one wave per node; Dn computed inline from ew gathers.
__global__ void stage2_kernel(const int* __restrict__ noff, const int* __restrict__ ncsr,
                              const float* __restrict__ ef, const float* __restrict__ ew,
                              const float* __restrict__ x, float* __restrict__ out) {
    int wid = (blockIdx.x * 256 + threadIdx.x) >> 6;
    if (wid >= N_NODES) return;
    int lane = threadIdx.x & 63;
    int group = lane >> 4;
    int gl = lane & 15;
    int s = noff[wid], t = noff[wid + 1];
    float4 acc = make_float4(0.f, 0.f, 0.f, 0.f);
    float dn = 0.f;
    for (int base = s; base < t; base += 64) {
        bool lv = (base + lane < t);
        int idx_l = lv ? ncsr[base + lane] : 0;
        if (lv) dn += ew[idx_l];
        int cnt = t - base; if (cnt > 64) cnt = 64;
        int steps = (cnt + 3) >> 2;
        for (int j = 0; j < steps; j++) {
            int p = 4 * j + group;
            int mi = __shfl(idx_l, p, 64);
            if (p < cnt) {
                float4 v = ((const float4*)ef)[(size_t)mi * 16 + gl];
                acc.x += v.x; acc.y += v.y; acc.z += v.z; acc.w += v.w;
            }
        }
    }
    for (int off = 1; off < 64; off <<= 1) dn += __shfl_xor(dn, off, 64);
    for (int off = 16; off < 64; off <<= 1) {
        acc.x += __shfl_xor(acc.x, off, 64);
        acc.y += __shfl_xor(acc.y, off, 64);
        acc.z += __shfl_xor(acc.z, off, 64);
        acc.w += __shfl_xor(acc.w, off, 64);
    }
    if (group == 0) {
        float dnr = (dn > 0.f) ? (1.0f / dn) : 0.f;
        float4 xv = ((const float4*)x)[(size_t)wid * 16 + gl];
        float4 r;
        r.x = 0.5f * (xv.x + dnr * acc.x);
        r.y = 0.5f * (xv.y + dnr * acc.y);
        r.z = 0.5f * (xv.z + dnr * acc.z);
        r.w = 0.5f * (xv.w + dnr * acc.w);
        ((float4*)out)[(size_t)wid * 16 + gl] = r;
    }
}

extern "C" void kernel_launch(void* const* d_in, const int* in_sizes, int n_in,
                              void* d_out, int out_size, void* d_ws, size_t ws_size,
                              hipStream_t stream) {
    const float* x        = (const float*)d_in[0];
    const int*   node_idx = (const int*)d_in[1];
    const int*   edge_idx = (const int*)d_in[2];
    const float* ew       = (const float*)d_in[3];
    float* out = (float*)d_out;

    char* ws = (char*)d_ws;
    int*          cnt      = (int*)(ws + 0);            // ncnt[100000] | ecnt[50000]
    int*          ncnt     = cnt;
    int*          ecnt     = cnt + N_NODES;
    unsigned int* ranks    = (unsigned int*)(ws + 600000);
    int*          noff     = (int*)(ws + 7000000);
    int*          eoff     = (int*)(ws + 7400016);
    int*          node_csr = (int*)(ws + 7600032);
    int*          edge_csr = (int*)(ws + 14000032);
    float*        ef       = (float*)(ws + 20400032);
    // scan scratch borrows the (pre-stage1) ef region:
    int* pn = (int*)ef;          // [25]
    int* pe = pn + 32;           // [13]
    int* bn = pn + 64;           // [25]
    int* be = pn + 96;           // [13]

    hipMemsetAsync(d_ws, 0, 600000, stream);   // counts only

    passA_kernel<<<(M_INC + 255) / 256, 256, 0, stream>>>(node_idx, edge_idx, ncnt, ecnt, ranks);
    scan_partial_kernel<<<N_TILES_N + N_TILES_E, 1024, 0, stream>>>(cnt, pn, pe);
    scan_base_kernel<<<1, 128, 0, stream>>>(pn, pe, bn, be, noff, eoff);
    scan_write_kernel<<<N_TILES_N + N_TILES_E, 1024, 0, stream>>>(cnt, bn, be, noff, eoff);
    fill_kernel<<<(M_INC + 255) / 256, 256, 0, stream>>>(node_idx, edge_idx, ranks,
                                                         noff, eoff, node_csr, edge_csr);
    stage1_kernel<<<(N_EDGES * 64 + 255) / 256, 256, 0, stream>>>(eoff, edge_csr, x, ef);
    stage2_kernel<<<(N_NODES * 64 + 255) / 256, 256, 0, stream>>>(noff, node_csr, ef, ew, x, out);
}